// Round 17
// baseline (87.811 us; speedup 1.0000x reference)
//
#include <hip/hip_runtime.h>
#include <hip/hip_bf16.h>
#include <stdint.h>

#define NROWS 8192
#define DIM 512

typedef short bf16x8 __attribute__((ext_vector_type(8)));
typedef float f32x4 __attribute__((ext_vector_type(4)));

__device__ __forceinline__ unsigned short f2bf(float f) {
    union { float f; uint32_t u; } c; c.f = f;
    uint32_t u = c.u;
    return (unsigned short)((u + 0x7FFFu + ((u >> 16) & 1u)) >> 16);
}

__device__ __forceinline__ void gload16(const unsigned short* g, unsigned short* l) {
    __builtin_amdgcn_global_load_lds((const __attribute__((address_space(1))) void*)g,
                                     (__attribute__((address_space(3))) void*)l,
                                     16, 0, 0);
}

// ---------------- Kernel 1: L2-normalize rows -> bf16; zero the scalar output --------
__global__ __launch_bounds__(256) void knorm(const float* __restrict__ in,
                                             unsigned short* __restrict__ out,
                                             float* __restrict__ loss_out) {
    if (blockIdx.x == 0 && threadIdx.x == 0) loss_out[0] = 0.0f;
    const int row  = (blockIdx.x << 2) + (threadIdx.x >> 6);
    const int lane = threadIdx.x & 63;
    const float4* src = (const float4*)(in + (size_t)row * DIM);
    float4 a = src[lane];
    float4 b = src[lane + 64];
    float ss = a.x*a.x + a.y*a.y + a.z*a.z + a.w*a.w
             + b.x*b.x + b.y*b.y + b.z*b.z + b.w*b.w;
    #pragma unroll
    for (int m = 1; m < 64; m <<= 1) ss += __shfl_xor(ss, m);
    const float inv = 1.0f / sqrtf(ss);
    ushort4* dst = (ushort4*)(out + (size_t)row * DIM);
    ushort4 o;
    o.x = f2bf(a.x*inv); o.y = f2bf(a.y*inv); o.z = f2bf(a.z*inv); o.w = f2bf(a.w*inv);
    dst[lane] = o;
    o.x = f2bf(b.x*inv); o.y = f2bf(b.y*inv); o.z = f2bf(b.z*inv); o.w = f2bf(b.w*inv);
    dst[lane + 64] = o;
}

// ---------------- Kernel 2: 8-phase 256^2 fused E*E^T (m201-template port) -----------
// 8 waves (2Mx4N), per-wave 128x64 output acc[8][4], BK=64, K=512 -> 8 K-tiles.
// LDS 128 KB: lds[2][4][128*64] = [region][slot: 0=Alo 1=Ahi 2=Blo 3=Bhi].
// Per tile t (region r=t&1), 4 phases; phase p: {ds_read (p0: 8 B-frags + A
// mi{0,1}; else A mi{2p,2p+1}) || stage ONE half-tile || 16 MFMA setprio-
// wrapped}, TWO raw barriers per phase. Stage offsets (-6..-3 phases ahead,
// order B-lo,B-hi,A-lo,A-hi): t.p0->Alo(t+1), p1->Ahi(t+1), p2->Blo(t+2),
// p3->Bhi(t+2). Ledger: at t.p0 after own stage, in-flight = 3 stages x 2
// loads -> vmcnt(6) once per tile, never drained before t=7; every half has
// >=3 phases of landing cover. WAR: B slots of region r freed at t.p0 (B
// persists in regs) -> write at t.p2 safe; A slots freed at tile end ->
// write 2 phases later. Swizzle/supertile/epilogue = proven R13 versions.
__global__ __launch_bounds__(512, 1) void kgemm(const unsigned short* __restrict__ E,
                                                float* __restrict__ part,
                                                float* __restrict__ pospart) {
    __shared__ unsigned short lds[2][4][128 * 64];

    const int tid = threadIdx.x;
    const int w = tid >> 6;          // 0..7
    const int l = tid & 63;

    // ---- block id -> (bi, bj): supertile triangle decode ----
    const int lin = (int)((blockIdx.x & 7) * 66 + (blockIdx.x >> 3));
    int rem = lin;
    int SI = -1, SJ = -1;
    #pragma unroll
    for (int s = 0; s < 10; s++) {
        constexpr int si_t[10] = {0,0,0,0,1,1,1,2,2,3};
        constexpr int sj_t[10] = {0,1,2,3,1,2,3,2,3,3};
        const int sz = (si_t[s] == sj_t[s]) ? 36 : 64;
        if (SI < 0) {
            if (rem < sz) { SI = si_t[s]; SJ = sj_t[s]; }
            else rem -= sz;
        }
    }
    int bi, bj;
    if (SI == SJ) {
        int x = 0;
        while (rem >= 8 - x) { rem -= 8 - x; x++; }
        bi = (SI << 3) + x; bj = (SI << 3) + x + rem;
    } else {
        bi = (SI << 3) + (rem >> 3);
        bj = (SJ << 3) + (rem & 7);
    }

    const int brow = bi << 8;
    const int bcol = bj << 8;
    const int wr = (w >> 2) << 7;        // 0 or 128
    const int wc = (w & 3) << 6;         // 0,64,128,192

    f32x4 acc[8][4];
    #pragma unroll
    for (int i = 0; i < 8; i++)
        #pragma unroll
        for (int j = 0; j < 4; j++) acc[i][j] = (f32x4)0.0f;

    // staging: thread covers chunks q*512+tid; row = q*64+(tid>>3), group = tid&7;
    // inverse-swizzled source group; LDS dest = wave-uniform base + lane*16.
    const int g_src = ((tid & 7) ^ ((tid >> 3) & 7)) << 3;   // ushort offset
    const int r_src = tid >> 3;                              // 0..63

    auto STAGE = [&](int reg, int slot, int rowbase, int kt) {
        const size_t colb = (size_t)((kt << 6) + g_src);
        #pragma unroll
        for (int q = 0; q < 2; q++) {
            gload16(E + (size_t)(rowbase + (q << 6) + r_src) * DIM + colb,
                    &lds[reg][slot][(q << 12) + (w << 9)]);
        }
    };

    // ds_read geometry (R13-proven XOR pattern; slot-local rows)
    const int as   = w >> 2;             // A slot: 0=lo,1=hi
    const int bs   = 2 + ((w >> 1) & 1); // B slot: 2=lo,3=hi
    const int bro  = (w & 1) << 6;       // B local row base (0 or 64)
    const int arow = l & 15;
    const int gsw0 = (((l >> 4)    ) ^ (l & 7)) << 3;   // kk=0 swizzled group off
    const int gsw1 = ((4 + (l >> 4)) ^ (l & 7)) << 3;   // kk=1

    bf16x8 bF[8], aF[4];

#define READ_A(S, MI0)                                                        \
    aF[0] = *(const bf16x8*)&S[((((MI0)    ) << 4) + arow) * 64 + gsw0];      \
    aF[1] = *(const bf16x8*)&S[((((MI0)    ) << 4) + arow) * 64 + gsw1];      \
    aF[2] = *(const bf16x8*)&S[((((MI0) + 1) << 4) + arow) * 64 + gsw0];      \
    aF[3] = *(const bf16x8*)&S[((((MI0) + 1) << 4) + arow) * 64 + gsw1];

#define MFMA16(MI0)                                                           \
    __builtin_amdgcn_s_setprio(1);                                            \
    _Pragma("unroll")                                                         \
    for (int ni = 0; ni < 4; ni++) {                                          \
        acc[(MI0)  ][ni] = __builtin_amdgcn_mfma_f32_16x16x32_bf16(           \
            aF[0], bF[ni*2+0], acc[(MI0)  ][ni], 0, 0, 0);                    \
        acc[(MI0)  ][ni] = __builtin_amdgcn_mfma_f32_16x16x32_bf16(           \
            aF[1], bF[ni*2+1], acc[(MI0)  ][ni], 0, 0, 0);                    \
        acc[(MI0)+1][ni] = __builtin_amdgcn_mfma_f32_16x16x32_bf16(           \
            aF[2], bF[ni*2+0], acc[(MI0)+1][ni], 0, 0, 0);                    \
        acc[(MI0)+1][ni] = __builtin_amdgcn_mfma_f32_16x16x32_bf16(           \
            aF[3], bF[ni*2+1], acc[(MI0)+1][ni], 0, 0, 0);                    \
    }                                                                         \
    __builtin_amdgcn_s_setprio(0);

#define LGKM0                                                                 \
    asm volatile("s_waitcnt lgkmcnt(0)" ::: "memory");                        \
    __builtin_amdgcn_sched_barrier(0);

    // ---- prologue: Blo0,Bhi0,Alo0,Ahi0,Blo1,Bhi1 (6 stages, 12 loads) ----
    STAGE(0, 2, bcol,       0);
    STAGE(0, 3, bcol + 128, 0);
    STAGE(0, 0, brow,       0);
    STAGE(0, 1, brow + 128, 0);
    STAGE(1, 2, bcol,       1);
    STAGE(1, 3, bcol + 128, 1);

    #pragma unroll
    for (int t = 0; t < 8; t++) {
        const int r = t & 1;
        const unsigned short* A = lds[r][as];
        const unsigned short* B = lds[r][bs];

        // ---- phase 0: publish tile t; read all B + A mi{0,1}; MFMA ----
        if (t < 7) {
            STAGE(r ^ 1, 0, brow, t + 1);                    // Alo(t+1)
            asm volatile("s_waitcnt vmcnt(6)" ::: "memory"); // tile t halves landed
        } else {
            asm volatile("s_waitcnt vmcnt(0)" ::: "memory");
        }
        __builtin_amdgcn_sched_barrier(0);
        __builtin_amdgcn_s_barrier();                        // publish to all waves
        #pragma unroll
        for (int ni = 0; ni < 4; ni++) {
            const int rb = (bro + (ni << 4) + arow) * 64;
            bF[ni*2+0] = *(const bf16x8*)&B[rb + gsw0];
            bF[ni*2+1] = *(const bf16x8*)&B[rb + gsw1];
        }
        READ_A(A, 0);
        LGKM0
        MFMA16(0)
        __builtin_amdgcn_s_barrier();

        // ---- phase 1 ----
        READ_A(A, 2);
        if (t < 7) STAGE(r ^ 1, 1, brow + 128, t + 1);       // Ahi(t+1)
        __builtin_amdgcn_s_barrier();
        LGKM0
        MFMA16(2)
        __builtin_amdgcn_s_barrier();

        // ---- phase 2 ----
        READ_A(A, 4);
        if (t < 6) STAGE(r, 2, bcol, t + 2);                 // Blo(t+2) (slot freed at p0)
        __builtin_amdgcn_s_barrier();
        LGKM0
        MFMA16(4)
        __builtin_amdgcn_s_barrier();

        // ---- phase 3 ----
        READ_A(A, 6);
        if (t < 6) STAGE(r, 3, bcol + 128, t + 2);           // Bhi(t+2)
        __builtin_amdgcn_s_barrier();
        LGKM0
        MFMA16(6)
        __builtin_amdgcn_s_barrier();
    }

    // ---- epilogue: exp(10*dot - 10), classify, LDS assemble, streaming store ----
    float* lds_row = (float*)&lds[0][0][0];       // [4][256]
    float* lds_col = lds_row + 1024;              // [2][256]
    float* lds_pos = lds_row + 2048;              // [4][256]

    __syncthreads();   // all main-loop LDS reads done before reuse

    if (bi == bj) {
        #pragma unroll
        for (int mi = 0; mi < 8; mi++) {
            #pragma unroll
            for (int rr = 0; rr < 4; rr++) {
                const int lrow = wr + (mi << 4) + ((l >> 4) << 2) + rr;
                const int gi = brow + lrow;
                float p = 0.0f, n = 0.0f;
                #pragma unroll
                for (int ni = 0; ni < 4; ni++) {
                    const int gj = bcol + wc + (ni << 4) + (l & 15);
                    const float e = __expf(fmaf(acc[mi][ni][rr], 10.0f, -10.0f));
                    if (gi == gj) {
                    } else if ((gi >> 2) == (gj >> 2)) {
                        p += e;
                    } else {
                        n += e;
                    }
                }
                #pragma unroll
                for (int m = 1; m < 16; m <<= 1) {
                    n += __shfl_xor(n, m);
                    p += __shfl_xor(p, m);
                }
                if ((l & 15) == 0) {
                    lds_row[((w & 3) << 8) + lrow] = n;
                    lds_pos[((w & 3) << 8) + lrow] = p;
                }
            }
        }
    } else {
        float c[4] = {0.0f, 0.0f, 0.0f, 0.0f};
        #pragma unroll
        for (int mi = 0; mi < 8; mi++) {
            #pragma unroll
            for (int rr = 0; rr < 4; rr++) {
                const int lrow = wr + (mi << 4) + ((l >> 4) << 2) + rr;
                float n = 0.0f;
                #pragma unroll
                for (int ni = 0; ni < 4; ni++) {
                    const float e = __expf(fmaf(acc[mi][ni][rr], 10.0f, -10.0f));
                    n += e;
                    c[ni] += e;
                }
                #pragma unroll
                for (int m = 1; m < 16; m <<= 1) n += __shfl_xor(n, m);
                if ((l & 15) == 0) lds_row[((w & 3) << 8) + lrow] = n;
            }
        }
        #pragma unroll
        for (int ni = 0; ni < 4; ni++) {
            c[ni] += __shfl_xor(c[ni], 16);
            c[ni] += __shfl_xor(c[ni], 32);
            if ((l >> 4) == 0)
                lds_col[((w >> 2) << 8) + wc + (ni << 4) + l] = c[ni];
        }
    }
    __syncthreads();

    if (tid < 256) {
        const float s = lds_row[tid] + lds_row[256 + tid]
                      + lds_row[512 + tid] + lds_row[768 + tid];
        part[((size_t)lin << 9) + tid] = s;
    } else {
        const int cc = tid - 256;
        if (bi != bj) {
            part[((size_t)lin << 9) + 256 + cc] = lds_col[cc] + lds_col[256 + cc];
        } else {
            pospart[(bi << 8) + cc] = lds_pos[cc] + lds_pos[256 + cc]
                                    + lds_pos[512 + cc] + lds_pos[768 + cc];
        }
    }
#undef READ_A
#undef MFMA16
#undef LGKM0
}

// ---------------- Kernel 3: gather partials, compute loss, reduce ----------------
__global__ __launch_bounds__(256) void kred(const float* __restrict__ part,
                                            const float* __restrict__ pospart,
                                            float* __restrict__ out) {
    const int T = blockIdx.x;
    const int r = threadIdx.x;

    auto linof = [](int a, int b) {   // a <= b, 0..31
        constexpr int base[4][4] = {{0, 36, 100, 164},
                                    {0, 228, 264, 328},
                                    {0, 0, 392, 428},
                                    {0, 0, 0, 492}};
        const int SI = a >> 3, SJ = b >> 3, x = a & 7, y = b & 7;
        int inner;
        if (SI == SJ) inner = (x << 3) - ((x * (x - 1)) >> 1) + (y - x);
        else          inner = (x << 3) + y;
        return base[SI][SJ] + inner;
    };

    float n = 0.0f;
    for (int bj = T; bj < 32; bj++)
        n += part[((size_t)linof(T, bj) << 9) + r];
    for (int bi = 0; bi < T; bi++)
        n += part[((size_t)linof(bi, T) << 9) + 256 + r];
    const float p = pospart[(T << 8) + r];

    float s = __logf(p + n + 1e-8f) - __logf(p);
    #pragma unroll
    for (int m = 1; m < 64; m <<= 1) s += __shfl_xor(s, m);
    __shared__ float red[4];
    if ((r & 63) == 0) red[r >> 6] = s;
    __syncthreads();
    if (r == 0)
        atomicAdd(out, (red[0] + red[1] + red[2] + red[3]) * (1.0f / (float)NROWS));
}

extern "C" void kernel_launch(void* const* d_in, const int* in_sizes, int n_in,
                              void* d_out, int out_size, void* d_ws, size_t ws_size,
                              hipStream_t stream) {
    (void)in_sizes; (void)n_in; (void)out_size; (void)ws_size;
    const float* emb = (const float*)d_in[0];
    unsigned short* En = (unsigned short*)d_ws;                          // 8 MB bf16
    float* pospart = (float*)((char*)d_ws + (size_t)NROWS * DIM * 2);    // 32 KB
    float* part    = pospart + 32 * 256;                                 // 1.05 MB

    knorm<<<NROWS / 4, 256, 0, stream>>>(emb, En, (float*)d_out);
    kgemm<<<528, 512, 0, stream>>>(En, part, pospart);
    kred<<<32, 256, 0, stream>>>(part, pospart, (float*)d_out);
}

// Round 18
// 75.077 us; speedup vs baseline: 1.1696x; 1.1696x over previous
//
#include <hip/hip_runtime.h>
#include <hip/hip_bf16.h>
#include <stdint.h>

#define NROWS 8192
#define DIM 512

typedef short bf16x8 __attribute__((ext_vector_type(8)));
typedef float f32x4 __attribute__((ext_vector_type(4)));

__device__ __forceinline__ unsigned short f2bf(float f) {
    union { float f; uint32_t u; } c; c.f = f;
    uint32_t u = c.u;
    return (unsigned short)((u + 0x7FFFu + ((u >> 16) & 1u)) >> 16);
}

__device__ __forceinline__ void gload16(const unsigned short* g, unsigned short* l) {
    __builtin_amdgcn_global_load_lds((const __attribute__((address_space(1))) void*)g,
                                     (__attribute__((address_space(3))) void*)l,
                                     16, 0, 0);
}

// ---------------- Kernel 1: L2-normalize rows -> bf16; zero out[0] + split-lin slots --
__global__ __launch_bounds__(256) void knorm(const float* __restrict__ in,
                                             unsigned short* __restrict__ out,
                                             float* __restrict__ part,
                                             float* __restrict__ loss_out) {
    if (blockIdx.x == 0 && threadIdx.x == 0) loss_out[0] = 0.0f;
    if (blockIdx.x < 16) {   // zero the 16 split-tile partial slots (quarters atomicAdd)
        part[((164 + blockIdx.x) << 9) + threadIdx.x] = 0.0f;
        part[((164 + blockIdx.x) << 9) + 256 + threadIdx.x] = 0.0f;
    }
    const int row  = (blockIdx.x << 2) + (threadIdx.x >> 6);
    const int lane = threadIdx.x & 63;
    const float4* src = (const float4*)(in + (size_t)row * DIM);
    float4 a = src[lane];
    float4 b = src[lane + 64];
    float ss = a.x*a.x + a.y*a.y + a.z*a.z + a.w*a.w
             + b.x*b.x + b.y*b.y + b.z*b.z + b.w*b.w;
    #pragma unroll
    for (int m = 1; m < 64; m <<= 1) ss += __shfl_xor(ss, m);
    const float inv = 1.0f / sqrtf(ss);
    ushort4* dst = (ushort4*)(out + (size_t)row * DIM);
    ushort4 o;
    o.x = f2bf(a.x*inv); o.y = f2bf(a.y*inv); o.z = f2bf(a.z*inv); o.w = f2bf(a.w*inv);
    dst[lane] = o;
    o.x = f2bf(b.x*inv); o.y = f2bf(b.y*inv); o.z = f2bf(b.z*inv); o.w = f2bf(b.w*inv);
    dst[lane + 64] = o;
}

// ---------------- Kernel 2: tail-balanced grid: 512 full 256^2 tiles + 64 quarters -----
// (R14 verbatim -- measured session best: kgemm 56.6us, total 74.8us.)
// blockIdx: xcd = id&7, slot = id>>3 (0..71). slot<64 -> full tile, lin = xcd*64+slot
// (+16 skip over split set). slot>=64 -> quarter q = xcd*8+(slot-64): parent
// p=q>>2 -> lin=164+p (supertile (0,3), all off-diagonal), quadrant (q>>1&1, q&1).
// Full path: BK=64, 8 convoys, counted vmcnt(4), proven 0-conflict swizzle,
// streaming-store partials. Quarter path: 128^2 4-wave geometry, atomicAdd
// into pre-zeroed slots. 512 heavy blocks = exactly 2 rounds; 64 light blocks
// (~T/4) fill the former 16-block third round.
__global__ __launch_bounds__(1024, 1) void kgemm(const unsigned short* __restrict__ E,
                                                 float* __restrict__ part,
                                                 float* __restrict__ pospart) {
    __shared__ unsigned short lds[2][2][256 * 64];   // full: 256 rows; quarter uses first 128

    const int tid = threadIdx.x;
    const int w = tid >> 6;          // 0..15
    const int l = tid & 63;
    const int xcd  = blockIdx.x & 7;
    const int slot = blockIdx.x >> 3;
    const int g_src = (l & 7) ^ (l >> 3);   // inverse-swizzled source 16B-group

    if (slot >= 64) {
        // ================= QUARTER: 128x128 pure-negative, 4 active waves ============
        const int q  = (xcd << 3) + (slot - 64);     // 0..63
        const int p  = q >> 2;                       // parent 0..15
        const int lin = 164 + p;
        const int bi = p >> 3, bj = 24 + (p & 7);
        const int brow = (bi << 8) + (((q >> 1) & 1) << 7);
        const int bcol = (bj << 8) + ((q & 1) << 7);
        const int qroff = (((q >> 1) & 1) << 7);     // row offset within parent
        const int qcoff = ((q & 1) << 7);            // col offset within parent
        const int wr = (w >> 1) << 6;                // valid for w<4
        const int wc = (w & 1) << 6;

        f32x4 acc[4][4];
        #pragma unroll
        for (int i = 0; i < 4; i++)
            #pragma unroll
            for (int j = 0; j < 4; j++) acc[i][j] = (f32x4)0.0f;

        auto STAGEQ = [&](int buf, int kt) {
            const size_t colb = (size_t)((kt << 6) + (g_src << 3));
            #pragma unroll
            for (int s = 0; s < 4; s++) {
                const int rb = (w << 5) + (s << 3);          // 0..127 for w<4
                const int r  = rb + (l >> 3);
                gload16(E + (size_t)(brow + r) * DIM + colb, &lds[buf][0][rb << 6]);
                gload16(E + (size_t)(bcol + r) * DIM + colb, &lds[buf][1][rb << 6]);
            }
        };
        auto COMPUTEQ = [&](int buf) {
            const unsigned short* sA = lds[buf][0];
            const unsigned short* sB = lds[buf][1];
            #pragma unroll
            for (int kk = 0; kk < 2; kk++) {
                bf16x8 aF[4], bF[4];
                const int gk  = (kk << 2) + (l >> 4);
                const int gsw = (gk ^ (l & 7)) << 3;
                #pragma unroll
                for (int mi = 0; mi < 4; mi++) {
                    const int rr = wr + (mi << 4) + (l & 15);
                    aF[mi] = *(const bf16x8*)&sA[(rr << 6) + gsw];
                }
                #pragma unroll
                for (int ni = 0; ni < 4; ni++) {
                    const int rr = wc + (ni << 4) + (l & 15);
                    bF[ni] = *(const bf16x8*)&sB[(rr << 6) + gsw];
                }
                #pragma unroll
                for (int mi = 0; mi < 4; mi++)
                    #pragma unroll
                    for (int ni = 0; ni < 4; ni++)
                        acc[mi][ni] = __builtin_amdgcn_mfma_f32_16x16x32_bf16(
                            aF[mi], bF[ni], acc[mi][ni], 0, 0, 0);
            }
        };

        if (w < 4) STAGEQ(0, 0);
        #pragma unroll
        for (int kt = 0; kt < 8; kt++) {
            if (kt > 0) __builtin_amdgcn_s_barrier();
            if (w < 4) {
                if (kt < 7) {
                    STAGEQ((kt + 1) & 1, kt + 1);
                    asm volatile("s_waitcnt vmcnt(8)" ::: "memory");
                } else {
                    asm volatile("s_waitcnt vmcnt(0)" ::: "memory");
                }
            }
            __builtin_amdgcn_sched_barrier(0);
            __builtin_amdgcn_s_barrier();
            if (w < 4) COMPUTEQ(kt & 1);
        }

        if (w < 4) {
            float c[4] = {0.0f, 0.0f, 0.0f, 0.0f};
            #pragma unroll
            for (int mi = 0; mi < 4; mi++) {
                #pragma unroll
                for (int r = 0; r < 4; r++) {
                    const int lrow = wr + (mi << 4) + ((l >> 4) << 2) + r;  // 0..127
                    float n = 0.0f;
                    #pragma unroll
                    for (int ni = 0; ni < 4; ni++) {
                        const float e = __expf(fmaf(acc[mi][ni][r], 10.0f, -10.0f));
                        n += e;
                        c[ni] += e;
                    }
                    #pragma unroll
                    for (int m = 1; m < 16; m <<= 1) n += __shfl_xor(n, m);
                    if ((l & 15) == 0)
                        atomicAdd(&part[((size_t)lin << 9) + qroff + lrow], n);
                }
            }
            #pragma unroll
            for (int ni = 0; ni < 4; ni++) {
                c[ni] += __shfl_xor(c[ni], 16);
                c[ni] += __shfl_xor(c[ni], 32);
                if ((l >> 4) == 0)
                    atomicAdd(&part[((size_t)lin << 9) + 256 + qcoff + wc + (ni << 4) + l],
                              c[ni]);
            }
        }
        return;
    }

    // ================= FULL: 256x256 tile =============================
    const int f   = (xcd << 6) + slot;               // 0..511
    const int lin = f + (f >= 164 ? 16 : 0);         // skip split set 164..179
    int rem = lin;
    int SI = -1, SJ = -1;
    #pragma unroll
    for (int s = 0; s < 10; s++) {
        constexpr int si_t[10] = {0,0,0,0,1,1,1,2,2,3};
        constexpr int sj_t[10] = {0,1,2,3,1,2,3,2,3,3};
        const int sz = (si_t[s] == sj_t[s]) ? 36 : 64;
        if (SI < 0) {
            if (rem < sz) { SI = si_t[s]; SJ = sj_t[s]; }
            else rem -= sz;
        }
    }
    int bi, bj;
    if (SI == SJ) {
        int x = 0;
        while (rem >= 8 - x) { rem -= 8 - x; x++; }
        bi = (SI << 3) + x; bj = (SI << 3) + x + rem;
    } else {
        bi = (SI << 3) + (rem >> 3);
        bj = (SJ << 3) + (rem & 7);
    }

    const int brow = bi << 8;
    const int bcol = bj << 8;
    const int wr = (w >> 2) << 6;
    const int wc = (w & 3) << 6;

    f32x4 acc[4][4];
    #pragma unroll
    for (int i = 0; i < 4; i++)
        #pragma unroll
        for (int j = 0; j < 4; j++) acc[i][j] = (f32x4)0.0f;

    auto STAGE = [&](int buf, int kt) {
        const size_t colb = (size_t)((kt << 6) + (g_src << 3));
        #pragma unroll
        for (int s = 0; s < 2; s++) {
            const int rb = (w << 4) + (s << 3);
            const int r  = rb + (l >> 3);
            gload16(E + (size_t)(brow + r) * DIM + colb, &lds[buf][0][rb << 6]);
            gload16(E + (size_t)(bcol + r) * DIM + colb, &lds[buf][1][rb << 6]);
        }
    };

    auto COMPUTE = [&](int buf) {
        const unsigned short* sA = lds[buf][0];
        const unsigned short* sB = lds[buf][1];
        #pragma unroll
        for (int kk = 0; kk < 2; kk++) {
            bf16x8 aF[4], bF[4];
            const int gk  = (kk << 2) + (l >> 4);
            const int gsw = (gk ^ (l & 7)) << 3;
            #pragma unroll
            for (int mi = 0; mi < 4; mi++) {
                const int rr = wr + (mi << 4) + (l & 15);
                aF[mi] = *(const bf16x8*)&sA[(rr << 6) + gsw];
            }
            #pragma unroll
            for (int ni = 0; ni < 4; ni++) {
                const int rr = wc + (ni << 4) + (l & 15);
                bF[ni] = *(const bf16x8*)&sB[(rr << 6) + gsw];
            }
            #pragma unroll
            for (int mi = 0; mi < 4; mi++)
                #pragma unroll
                for (int ni = 0; ni < 4; ni++)
                    acc[mi][ni] = __builtin_amdgcn_mfma_f32_16x16x32_bf16(
                        aF[mi], bF[ni], acc[mi][ni], 0, 0, 0);
        }
    };

    STAGE(0, 0);
    #pragma unroll
    for (int kt = 0; kt < 8; kt++) {
        if (kt > 0) __builtin_amdgcn_s_barrier();
        if (kt < 7) {
            STAGE((kt + 1) & 1, kt + 1);
            asm volatile("s_waitcnt vmcnt(4)" ::: "memory");
        } else {
            asm volatile("s_waitcnt vmcnt(0)" ::: "memory");
        }
        __builtin_amdgcn_sched_barrier(0);
        __builtin_amdgcn_s_barrier();
        COMPUTE(kt & 1);
    }

    float* lds_row = (float*)&lds[0][0][0];       // [4][256]
    float* lds_col = lds_row + 1024;              // [4][256]
    float* lds_pos = lds_row + 2048;              // [4][256]

    __syncthreads();

    if (bi == bj) {
        #pragma unroll
        for (int mi = 0; mi < 4; mi++) {
            #pragma unroll
            for (int r = 0; r < 4; r++) {
                const int lrow = wr + (mi << 4) + ((l >> 4) << 2) + r;
                const int gi = brow + lrow;
                float p = 0.0f, n = 0.0f;
                #pragma unroll
                for (int ni = 0; ni < 4; ni++) {
                    const int gj = bcol + wc + (ni << 4) + (l & 15);
                    const float e = __expf(fmaf(acc[mi][ni][r], 10.0f, -10.0f));
                    if (gi == gj) {
                    } else if ((gi >> 2) == (gj >> 2)) {
                        p += e;
                    } else {
                        n += e;
                    }
                }
                #pragma unroll
                for (int m = 1; m < 16; m <<= 1) {
                    n += __shfl_xor(n, m);
                    p += __shfl_xor(p, m);
                }
                if ((l & 15) == 0) {
                    lds_row[((w & 3) << 8) + lrow] = n;
                    lds_pos[((w & 3) << 8) + lrow] = p;
                }
            }
        }
    } else {
        float c[4] = {0.0f, 0.0f, 0.0f, 0.0f};
        #pragma unroll
        for (int mi = 0; mi < 4; mi++) {
            #pragma unroll
            for (int r = 0; r < 4; r++) {
                const int lrow = wr + (mi << 4) + ((l >> 4) << 2) + r;
                float n = 0.0f;
                #pragma unroll
                for (int ni = 0; ni < 4; ni++) {
                    const float e = __expf(fmaf(acc[mi][ni][r], 10.0f, -10.0f));
                    n += e;
                    c[ni] += e;
                }
                #pragma unroll
                for (int m = 1; m < 16; m <<= 1) n += __shfl_xor(n, m);
                if ((l & 15) == 0) lds_row[((w & 3) << 8) + lrow] = n;
            }
        }
        #pragma unroll
        for (int ni = 0; ni < 4; ni++) {
            c[ni] += __shfl_xor(c[ni], 16);
            c[ni] += __shfl_xor(c[ni], 32);
            if ((l >> 4) == 0)
                lds_col[((w >> 2) << 8) + wc + (ni << 4) + l] = c[ni];
        }
    }
    __syncthreads();

    if (tid < 256) {
        const float s = lds_row[tid] + lds_row[256 + tid]
                      + lds_row[512 + tid] + lds_row[768 + tid];
        part[((size_t)lin << 9) + tid] = s;
    } else if (tid < 512) {
        if (bi != bj) {
            const int cc = tid - 256;
            const float s = lds_col[cc] + lds_col[256 + cc]
                          + lds_col[512 + cc] + lds_col[768 + cc];
            part[((size_t)lin << 9) + 256 + cc] = s;
        }
    } else if (tid < 768) {
        if (bi == bj) {
            const int rr = tid - 512;
            const float s = lds_pos[rr] + lds_pos[256 + rr]
                          + lds_pos[512 + rr] + lds_pos[768 + rr];
            pospart[(bi << 8) + rr] = s;
        }
    }
}

// ---------------- Kernel 3: gather partials, compute loss, reduce ----------------
// 64 blocks x 128 threads: block b covers rows T*256 + (b&1)*128 .. +128,
// T = b>>1 (2x the CU coverage of the 32-block version; ~1.5us saved).
__global__ __launch_bounds__(128) void kred(const float* __restrict__ part,
                                            const float* __restrict__ pospart,
                                            float* __restrict__ out) {
    const int T = blockIdx.x >> 1;
    const int r = ((blockIdx.x & 1) << 7) + threadIdx.x;   // 0..255 within T's group

    auto linof = [](int a, int b) {   // a <= b, 0..31
        constexpr int base[4][4] = {{0, 36, 100, 164},
                                    {0, 228, 264, 328},
                                    {0, 0, 392, 428},
                                    {0, 0, 0, 492}};
        const int SI = a >> 3, SJ = b >> 3, x = a & 7, y = b & 7;
        int inner;
        if (SI == SJ) inner = (x << 3) - ((x * (x - 1)) >> 1) + (y - x);
        else          inner = (x << 3) + y;
        return base[SI][SJ] + inner;
    };

    float n = 0.0f;
    for (int bj = T; bj < 32; bj++)
        n += part[((size_t)linof(T, bj) << 9) + r];
    for (int bi = 0; bi < T; bi++)
        n += part[((size_t)linof(bi, T) << 9) + 256 + r];
    const float p = pospart[(T << 8) + r];

    float s = __logf(p + n + 1e-8f) - __logf(p);
    #pragma unroll
    for (int m = 1; m < 64; m <<= 1) s += __shfl_xor(s, m);
    __shared__ float red[2];
    if ((threadIdx.x & 63) == 0) red[threadIdx.x >> 6] = s;
    __syncthreads();
    if (threadIdx.x == 0)
        atomicAdd(out, (red[0] + red[1]) * (1.0f / (float)NROWS));
}

extern "C" void kernel_launch(void* const* d_in, const int* in_sizes, int n_in,
                              void* d_out, int out_size, void* d_ws, size_t ws_size,
                              hipStream_t stream) {
    (void)in_sizes; (void)n_in; (void)out_size; (void)ws_size;
    const float* emb = (const float*)d_in[0];
    unsigned short* En = (unsigned short*)d_ws;                          // 8 MB bf16
    float* pospart = (float*)((char*)d_ws + (size_t)NROWS * DIM * 2);    // 32 KB
    float* part    = pospart + 32 * 256;                                 // 1.05 MB

    knorm<<<NROWS / 4, 256, 0, stream>>>(emb, En, part, (float*)d_out);
    kgemm<<<576, 1024, 0, stream>>>(En, part, pospart);
    kred<<<64, 128, 0, stream>>>(part, pospart, (float*)d_out);
}

// Round 19
// 65.757 us; speedup vs baseline: 1.3354x; 1.1417x over previous
//
#include <hip/hip_runtime.h>
#include <hip/hip_bf16.h>
#include <stdint.h>

#define NROWS 8192
#define DIM 512

typedef short bf16x8 __attribute__((ext_vector_type(8)));
typedef float f32x4 __attribute__((ext_vector_type(4)));

__device__ __forceinline__ unsigned short f2bf(float f) {
    union { float f; uint32_t u; } c; c.f = f;
    uint32_t u = c.u;
    return (unsigned short)((u + 0x7FFFu + ((u >> 16) & 1u)) >> 16);
}

__device__ __forceinline__ void gload16(const unsigned short* g, unsigned short* l) {
    __builtin_amdgcn_global_load_lds((const __attribute__((address_space(1))) void*)g,
                                     (__attribute__((address_space(3))) void*)l,
                                     16, 0, 0);
}

// ---------------- Kernel 1: L2-normalize rows -> bf16; zero out[0] + split-lin slots --
__global__ __launch_bounds__(256) void knorm(const float* __restrict__ in,
                                             unsigned short* __restrict__ out,
                                             float* __restrict__ part,
                                             float* __restrict__ loss_out) {
    if (blockIdx.x == 0 && threadIdx.x == 0) loss_out[0] = 0.0f;
    if (blockIdx.x < 16) {   // zero the 16 split-tile partial slots (quarters atomicAdd)
        part[((164 + blockIdx.x) << 9) + threadIdx.x] = 0.0f;
        part[((164 + blockIdx.x) << 9) + 256 + threadIdx.x] = 0.0f;
    }
    const int row  = (blockIdx.x << 2) + (threadIdx.x >> 6);
    const int lane = threadIdx.x & 63;
    const float4* src = (const float4*)(in + (size_t)row * DIM);
    float4 a = src[lane];
    float4 b = src[lane + 64];
    float ss = a.x*a.x + a.y*a.y + a.z*a.z + a.w*a.w
             + b.x*b.x + b.y*b.y + b.z*b.z + b.w*b.w;
    #pragma unroll
    for (int m = 1; m < 64; m <<= 1) ss += __shfl_xor(ss, m);
    const float inv = 1.0f / sqrtf(ss);
    ushort4* dst = (ushort4*)(out + (size_t)row * DIM);
    ushort4 o;
    o.x = f2bf(a.x*inv); o.y = f2bf(a.y*inv); o.z = f2bf(a.z*inv); o.w = f2bf(a.w*inv);
    dst[lane] = o;
    o.x = f2bf(b.x*inv); o.y = f2bf(b.y*inv); o.z = f2bf(b.z*inv); o.w = f2bf(b.w*inv);
    dst[lane + 64] = o;
}

// ---------------- Kernel 2: tail-balanced grid: 512 full 256^2 tiles + 64 quarters -----
// Full path = R13/R14 verbatim. Quarter path NOW USES ALL 16 WAVES (R15 lesson:
// the 4-wave version ran at ~full-tile time because issue rate was quartered):
// 4x4 wave grid over 128x128, per-wave 32x32 output acc[2][2], 1 gload16 per
// thread per operand per K-step (vmcnt(2)), same proven swizzle (row&7==l>>3
// in both geometries so g_src/gsw expressions are identical). Quarter results
// atomicAdd into the 16 pre-zeroed split slots (~64K atomics total).
__global__ __launch_bounds__(1024, 1) void kgemm(const unsigned short* __restrict__ E,
                                                 float* __restrict__ part,
                                                 float* __restrict__ pospart) {
    __shared__ unsigned short lds[2][2][256 * 64];   // full: 256 rows; quarter uses first 128

    const int tid = threadIdx.x;
    const int w = tid >> 6;          // 0..15
    const int l = tid & 63;
    const int xcd  = blockIdx.x & 7;
    const int slot = blockIdx.x >> 3;
    const int g_src = (l & 7) ^ (l >> 3);   // inverse-swizzled source 16B-group

    if (slot >= 64) {
        // ========== QUARTER: 128x128 pure-negative, ALL 16 waves (4x4 grid) ==========
        const int q  = (xcd << 3) + (slot - 64);     // 0..63
        const int p  = q >> 2;                       // parent 0..15
        const int lin = 164 + p;
        const int bi = p >> 3, bj = 24 + (p & 7);
        const int brow = (bi << 8) + (((q >> 1) & 1) << 7);
        const int bcol = (bj << 8) + ((q & 1) << 7);
        const int qroff = (((q >> 1) & 1) << 7);     // row offset within parent
        const int qcoff = ((q & 1) << 7);            // col offset within parent
        const int wr = (w >> 2) << 5;                // 0,32,64,96
        const int wc = (w & 3) << 5;                 // 0,32,64,96

        f32x4 acc[2][2];
        #pragma unroll
        for (int i = 0; i < 2; i++)
            #pragma unroll
            for (int j = 0; j < 2; j++) acc[i][j] = (f32x4)0.0f;

        // staging: thread tid covers row tid>>3 (0..127); wave slab = base + lane*16
        auto STAGEQ = [&](int buf, int kt) {
            const size_t colb = (size_t)((kt << 6) + (g_src << 3));
            const int r = (w << 3) + (l >> 3);                   // 0..127
            gload16(E + (size_t)(brow + r) * DIM + colb, &lds[buf][0][w << 9]);
            gload16(E + (size_t)(bcol + r) * DIM + colb, &lds[buf][1][w << 9]);
        };
        auto COMPUTEQ = [&](int buf) {
            const unsigned short* sA = lds[buf][0];
            const unsigned short* sB = lds[buf][1];
            #pragma unroll
            for (int kk = 0; kk < 2; kk++) {
                bf16x8 aF[2], bF[2];
                const int gk  = (kk << 2) + (l >> 4);
                const int gsw = (gk ^ (l & 7)) << 3;
                #pragma unroll
                for (int mi = 0; mi < 2; mi++) {
                    const int rr = wr + (mi << 4) + (l & 15);
                    aF[mi] = *(const bf16x8*)&sA[(rr << 6) + gsw];
                }
                #pragma unroll
                for (int ni = 0; ni < 2; ni++) {
                    const int rr = wc + (ni << 4) + (l & 15);
                    bF[ni] = *(const bf16x8*)&sB[(rr << 6) + gsw];
                }
                #pragma unroll
                for (int mi = 0; mi < 2; mi++)
                    #pragma unroll
                    for (int ni = 0; ni < 2; ni++)
                        acc[mi][ni] = __builtin_amdgcn_mfma_f32_16x16x32_bf16(
                            aF[mi], bF[ni], acc[mi][ni], 0, 0, 0);
            }
        };

        STAGEQ(0, 0);
        #pragma unroll
        for (int kt = 0; kt < 8; kt++) {
            if (kt > 0) __builtin_amdgcn_s_barrier();
            if (kt < 7) {
                STAGEQ((kt + 1) & 1, kt + 1);
                asm volatile("s_waitcnt vmcnt(2)" ::: "memory");
            } else {
                asm volatile("s_waitcnt vmcnt(0)" ::: "memory");
            }
            __builtin_amdgcn_sched_barrier(0);
            __builtin_amdgcn_s_barrier();
            COMPUTEQ(kt & 1);
        }

        float c[2] = {0.0f, 0.0f};
        #pragma unroll
        for (int mi = 0; mi < 2; mi++) {
            #pragma unroll
            for (int r = 0; r < 4; r++) {
                const int lrow = wr + (mi << 4) + ((l >> 4) << 2) + r;  // 0..127
                float n = 0.0f;
                #pragma unroll
                for (int ni = 0; ni < 2; ni++) {
                    const float e = __expf(fmaf(acc[mi][ni][r], 10.0f, -10.0f));
                    n += e;
                    c[ni] += e;
                }
                #pragma unroll
                for (int m = 1; m < 16; m <<= 1) n += __shfl_xor(n, m);
                if ((l & 15) == 0)
                    atomicAdd(&part[((size_t)lin << 9) + qroff + lrow], n);
            }
        }
        #pragma unroll
        for (int ni = 0; ni < 2; ni++) {
            c[ni] += __shfl_xor(c[ni], 16);
            c[ni] += __shfl_xor(c[ni], 32);
            if ((l >> 4) == 0)
                atomicAdd(&part[((size_t)lin << 9) + 256 + qcoff + wc + (ni << 4) + l],
                          c[ni]);
        }
        return;
    }

    // ================= FULL: 256x256 tile =============================
    const int f   = (xcd << 6) + slot;               // 0..511
    const int lin = f + (f >= 164 ? 16 : 0);         // skip split set 164..179
    int rem = lin;
    int SI = -1, SJ = -1;
    #pragma unroll
    for (int s = 0; s < 10; s++) {
        constexpr int si_t[10] = {0,0,0,0,1,1,1,2,2,3};
        constexpr int sj_t[10] = {0,1,2,3,1,2,3,2,3,3};
        const int sz = (si_t[s] == sj_t[s]) ? 36 : 64;
        if (SI < 0) {
            if (rem < sz) { SI = si_t[s]; SJ = sj_t[s]; }
            else rem -= sz;
        }
    }
    int bi, bj;
    if (SI == SJ) {
        int x = 0;
        while (rem >= 8 - x) { rem -= 8 - x; x++; }
        bi = (SI << 3) + x; bj = (SI << 3) + x + rem;
    } else {
        bi = (SI << 3) + (rem >> 3);
        bj = (SJ << 3) + (rem & 7);
    }

    const int brow = bi << 8;
    const int bcol = bj << 8;
    const int wr = (w >> 2) << 6;
    const int wc = (w & 3) << 6;

    f32x4 acc[4][4];
    #pragma unroll
    for (int i = 0; i < 4; i++)
        #pragma unroll
        for (int j = 0; j < 4; j++) acc[i][j] = (f32x4)0.0f;

    auto STAGE = [&](int buf, int kt) {
        const size_t colb = (size_t)((kt << 6) + (g_src << 3));
        #pragma unroll
        for (int s = 0; s < 2; s++) {
            const int rb = (w << 4) + (s << 3);
            const int r  = rb + (l >> 3);
            gload16(E + (size_t)(brow + r) * DIM + colb, &lds[buf][0][rb << 6]);
            gload16(E + (size_t)(bcol + r) * DIM + colb, &lds[buf][1][rb << 6]);
        }
    };

    auto COMPUTE = [&](int buf) {
        const unsigned short* sA = lds[buf][0];
        const unsigned short* sB = lds[buf][1];
        #pragma unroll
        for (int kk = 0; kk < 2; kk++) {
            bf16x8 aF[4], bF[4];
            const int gk  = (kk << 2) + (l >> 4);
            const int gsw = (gk ^ (l & 7)) << 3;
            #pragma unroll
            for (int mi = 0; mi < 4; mi++) {
                const int rr = wr + (mi << 4) + (l & 15);
                aF[mi] = *(const bf16x8*)&sA[(rr << 6) + gsw];
            }
            #pragma unroll
            for (int ni = 0; ni < 4; ni++) {
                const int rr = wc + (ni << 4) + (l & 15);
                bF[ni] = *(const bf16x8*)&sB[(rr << 6) + gsw];
            }
            #pragma unroll
            for (int mi = 0; mi < 4; mi++)
                #pragma unroll
                for (int ni = 0; ni < 4; ni++)
                    acc[mi][ni] = __builtin_amdgcn_mfma_f32_16x16x32_bf16(
                        aF[mi], bF[ni], acc[mi][ni], 0, 0, 0);
        }
    };

    STAGE(0, 0);
    #pragma unroll
    for (int kt = 0; kt < 8; kt++) {
        if (kt > 0) __builtin_amdgcn_s_barrier();
        if (kt < 7) {
            STAGE((kt + 1) & 1, kt + 1);
            asm volatile("s_waitcnt vmcnt(4)" ::: "memory");
        } else {
            asm volatile("s_waitcnt vmcnt(0)" ::: "memory");
        }
        __builtin_amdgcn_sched_barrier(0);
        __builtin_amdgcn_s_barrier();
        COMPUTE(kt & 1);
    }

    float* lds_row = (float*)&lds[0][0][0];       // [4][256]
    float* lds_col = lds_row + 1024;              // [4][256]
    float* lds_pos = lds_row + 2048;              // [4][256]

    __syncthreads();

    if (bi == bj) {
        #pragma unroll
        for (int mi = 0; mi < 4; mi++) {
            #pragma unroll
            for (int r = 0; r < 4; r++) {
                const int lrow = wr + (mi << 4) + ((l >> 4) << 2) + r;
                const int gi = brow + lrow;
                float p = 0.0f, n = 0.0f;
                #pragma unroll
                for (int ni = 0; ni < 4; ni++) {
                    const int gj = bcol + wc + (ni << 4) + (l & 15);
                    const float e = __expf(fmaf(acc[mi][ni][r], 10.0f, -10.0f));
                    if (gi == gj) {
                    } else if ((gi >> 2) == (gj >> 2)) {
                        p += e;
                    } else {
                        n += e;
                    }
                }
                #pragma unroll
                for (int m = 1; m < 16; m <<= 1) {
                    n += __shfl_xor(n, m);
                    p += __shfl_xor(p, m);
                }
                if ((l & 15) == 0) {
                    lds_row[((w & 3) << 8) + lrow] = n;
                    lds_pos[((w & 3) << 8) + lrow] = p;
                }
            }
        }
    } else {
        float c[4] = {0.0f, 0.0f, 0.0f, 0.0f};
        #pragma unroll
        for (int mi = 0; mi < 4; mi++) {
            #pragma unroll
            for (int r = 0; r < 4; r++) {
                const int lrow = wr + (mi << 4) + ((l >> 4) << 2) + r;
                float n = 0.0f;
                #pragma unroll
                for (int ni = 0; ni < 4; ni++) {
                    const float e = __expf(fmaf(acc[mi][ni][r], 10.0f, -10.0f));
                    n += e;
                    c[ni] += e;
                }
                #pragma unroll
                for (int m = 1; m < 16; m <<= 1) n += __shfl_xor(n, m);
                if ((l & 15) == 0) lds_row[((w & 3) << 8) + lrow] = n;
            }
        }
        #pragma unroll
        for (int ni = 0; ni < 4; ni++) {
            c[ni] += __shfl_xor(c[ni], 16);
            c[ni] += __shfl_xor(c[ni], 32);
            if ((l >> 4) == 0)
                lds_col[((w >> 2) << 8) + wc + (ni << 4) + l] = c[ni];
        }
    }
    __syncthreads();

    if (tid < 256) {
        const float s = lds_row[tid] + lds_row[256 + tid]
                      + lds_row[512 + tid] + lds_row[768 + tid];
        part[((size_t)lin << 9) + tid] = s;
    } else if (tid < 512) {
        if (bi != bj) {
            const int cc = tid - 256;
            const float s = lds_col[cc] + lds_col[256 + cc]
                          + lds_col[512 + cc] + lds_col[768 + cc];
            part[((size_t)lin << 9) + 256 + cc] = s;
        }
    } else if (tid < 768) {
        if (bi == bj) {
            const int rr = tid - 512;
            const float s = lds_pos[rr] + lds_pos[256 + rr]
                          + lds_pos[512 + rr] + lds_pos[768 + rr];
            pospart[(bi << 8) + rr] = s;
        }
    }
}

// ---------------- Kernel 3: gather partials, compute loss, reduce ----------------
__global__ __launch_bounds__(128) void kred(const float* __restrict__ part,
                                            const float* __restrict__ pospart,
                                            float* __restrict__ out) {
    const int T = blockIdx.x >> 1;
    const int r = ((blockIdx.x & 1) << 7) + threadIdx.x;   // 0..255 within T's group

    auto linof = [](int a, int b) {   // a <= b, 0..31
        constexpr int base[4][4] = {{0, 36, 100, 164},
                                    {0, 228, 264, 328},
                                    {0, 0, 392, 428},
                                    {0, 0, 0, 492}};
        const int SI = a >> 3, SJ = b >> 3, x = a & 7, y = b & 7;
        int inner;
        if (SI == SJ) inner = (x << 3) - ((x * (x - 1)) >> 1) + (y - x);
        else          inner = (x << 3) + y;
        return base[SI][SJ] + inner;
    };

    float n = 0.0f;
    for (int bj = T; bj < 32; bj++)
        n += part[((size_t)linof(T, bj) << 9) + r];
    for (int bi = 0; bi < T; bi++)
        n += part[((size_t)linof(bi, T) << 9) + 256 + r];
    const float p = pospart[(T << 8) + r];

    float s = __logf(p + n + 1e-8f) - __logf(p);
    #pragma unroll
    for (int m = 1; m < 64; m <<= 1) s += __shfl_xor(s, m);
    __shared__ float red[2];
    if ((threadIdx.x & 63) == 0) red[threadIdx.x >> 6] = s;
    __syncthreads();
    if (threadIdx.x == 0)
        atomicAdd(out, (red[0] + red[1]) * (1.0f / (float)NROWS));
}

extern "C" void kernel_launch(void* const* d_in, const int* in_sizes, int n_in,
                              void* d_out, int out_size, void* d_ws, size_t ws_size,
                              hipStream_t stream) {
    (void)in_sizes; (void)n_in; (void)out_size; (void)ws_size;
    const float* emb = (const float*)d_in[0];
    unsigned short* En = (unsigned short*)d_ws;                          // 8 MB bf16
    float* pospart = (float*)((char*)d_ws + (size_t)NROWS * DIM * 2);    // 32 KB
    float* part    = pospart + 32 * 256;                                 // 1.05 MB

    knorm<<<NROWS / 4, 256, 0, stream>>>(emb, En, part, (float*)d_out);
    kgemm<<<576, 1024, 0, stream>>>(En, part, pospart);
    kred<<<64, 128, 0, stream>>>(part, pospart, (float*)d_out);
}